// Round 2
// baseline (832.200 us; speedup 1.0000x reference)
//
#include <hip/hip_runtime.h>
#include <cstdint>
#include <cstddef>

#define BB 4
#define NN 4096
#define DD 768
#define EE 2304      // 3*DD
#define MTOT 16384   // BB*NN
static constexpr float ATT_SCALE = 0.03608439182435161f;  // 1/sqrt(768)

typedef _Float16 v8h __attribute__((ext_vector_type(8)));
typedef _Float16 v4h __attribute__((ext_vector_type(4)));
typedef float v4f __attribute__((ext_vector_type(4)));

// Async global->LDS, 16B per lane. HW semantics: LDS dest = wave-uniform base +
// lane*16, so callers MUST pass lds addresses that are exactly base+lane*16 in
// lane order within each wave.
__device__ __forceinline__ void async_copy16(void* lds, const void* gmem) {
  __builtin_amdgcn_global_load_lds(
      (const __attribute__((address_space(1))) uint32_t*)(uintptr_t)gmem,
      (__attribute__((address_space(3))) uint32_t*)(uintptr_t)lds,
      16, 0, 0);
}

enum { EPI_QKV = 0, EPI_F32 = 1, EPI_F16 = 2, EPI_OUT = 3 };

// C[M,N] = A[M,K] @ Bt[N,K]^T.  A row-major (lda), Bt row-major (ldb) i.e. B
// stored n-major so both tiles stage identically.  128x128 tile, BK=32,
// 256 threads = 4 waves in 2x2, each wave 4x4 tiles of 16x16x32 f16 MFMA.
// Grid: (M/128, N/128). M,N multiples of 128; K multiple of 32.
// lda/ldb are PHYSICAL row strides in f16 elements (may exceed K).
template <int EPI>
__global__ __launch_bounds__(256) void gemm128(
    const _Float16* __restrict__ A, int lda,
    const _Float16* __restrict__ Bt, int ldb,
    int K,
    float* __restrict__ c_f32,
    _Float16* __restrict__ c_f16,
    int ldc,
    const float* __restrict__ bias,
    _Float16* __restrict__ q_out,
    _Float16* __restrict__ k_out,
    _Float16* __restrict__ v_out) {
  __shared__ __align__(16) _Float16 As[128 * 32];
  __shared__ __align__(16) _Float16 Bs[128 * 32];

  const int tid = threadIdx.x;
  const int wid = tid >> 6;
  const int lane = tid & 63;
  const int wr = wid >> 1, wc = wid & 1;       // wave grid 2x2 (64x64 each)
  const int lq = lane >> 4, lr = lane & 15;    // quad, row-in-tile
  const int m0 = blockIdx.x * 128, n0 = blockIdx.y * 128;

  const _Float16* Ab = A + (size_t)m0 * lda;
  const _Float16* Bb = Bt + (size_t)n0 * ldb;

  v4f acc[4][4] = {};

  for (int k0 = 0; k0 < K; k0 += 32) {
    // Stage 8KB A-tile + 8KB B-tile: 2 chunks of 16B per thread each.
    // chunk c in [0,512): row r=c/4 of the tile, 16B sub-chunk kc=c%4.
    // LDS offset = c*16 bytes == per-wave contiguous (c = i*256 + wid*64 + lane).
#pragma unroll
    for (int i = 0; i < 2; ++i) {
      const int c = i * 256 + tid;
      const int r = c >> 2, kc = c & 3;
      async_copy16(As + (size_t)c * 8, Ab + (size_t)r * lda + (k0 + kc * 8));
      async_copy16(Bs + (size_t)c * 8, Bb + (size_t)r * ldb + (k0 + kc * 8));
    }
    __syncthreads();  // compiler emits vmcnt(0) drain before s_barrier

    v8h af[4], bf[4];
#pragma unroll
    for (int t = 0; t < 4; ++t) {
      // A frag: lane holds A[m=lr][k=lq*8+j]; contiguous 16B -> ds_read_b128
      af[t] = *(const v8h*)(As + ((wr * 64 + t * 16 + lr) * 32 + lq * 8));
      // B frag: lane holds B[k=lq*8+j][n=lr]; Bs is n-major so contiguous too
      bf[t] = *(const v8h*)(Bs + ((wc * 64 + t * 16 + lr) * 32 + lq * 8));
    }
#pragma unroll
    for (int mt = 0; mt < 4; ++mt)
#pragma unroll
      for (int nt = 0; nt < 4; ++nt)
        acc[mt][nt] = __builtin_amdgcn_mfma_f32_16x16x32_f16(
            af[mt], bf[nt], acc[mt][nt], 0, 0, 0);
    __syncthreads();
  }

  // Epilogue. C/D frag: col = lane&15, row = (lane>>4)*4 + reg (verified m89/m91).
#pragma unroll
  for (int mt = 0; mt < 4; ++mt) {
#pragma unroll
    for (int nt = 0; nt < 4; ++nt) {
#pragma unroll
      for (int rg = 0; rg < 4; ++rg) {
        const int gm = m0 + wr * 64 + mt * 16 + lq * 4 + rg;
        const int gn = n0 + wc * 64 + nt * 16 + lr;
        float v = acc[mt][nt][rg];
        if constexpr (EPI == EPI_QKV) {
          v += bias[gn];
          // 768 and 1536 are multiples of 128 -> branch is block-uniform
          if (gn < DD) {
            q_out[(size_t)gm * DD + gn] = (_Float16)(v * ATT_SCALE);
          } else if (gn < 2 * DD) {
            k_out[(size_t)gm * DD + (gn - DD)] = (_Float16)v;
          } else {
            v_out[(size_t)gm * DD + (gn - 2 * DD)] = (_Float16)v;
          }
        } else if constexpr (EPI == EPI_F32) {
          c_f32[(size_t)gm * ldc + gn] = v;
        } else if constexpr (EPI == EPI_F16) {
          c_f16[(size_t)gm * ldc + gn] = (_Float16)v;
        } else {  // EPI_OUT
          c_f32[(size_t)gm * ldc + gn] = v + bias[gn];
        }
      }
    }
  }
}

// Row softmax over S[4096][4096] f32; writes P f16 IN PLACE into the first half
// of each row (safe: all loads complete before the max-reduction barrier; each
// row is owned by exactly one block). The resulting f16 matrix has a PHYSICAL
// row stride of 2*NN f16 elements (= the fp32 row's byte size).
__global__ __launch_bounds__(256) void softmax_rows(float* __restrict__ S) {
  const int row = blockIdx.x;
  const float* s = S + (size_t)row * NN;
  _Float16* p = (_Float16*)(S + (size_t)row * NN);  // f16 view of same row
  const int tid = threadIdx.x;
  const int lane = tid & 63, wid = tid >> 6;

  v4f v[4];
  float m = -3.0e38f;
#pragma unroll
  for (int i = 0; i < 4; ++i) {
    v[i] = ((const v4f*)s)[tid + i * 256];
    m = fmaxf(m, fmaxf(fmaxf(v[i][0], v[i][1]), fmaxf(v[i][2], v[i][3])));
  }
#pragma unroll
  for (int off = 32; off > 0; off >>= 1) m = fmaxf(m, __shfl_xor(m, off));
  __shared__ float redm[4], reds[4];
  if (lane == 0) redm[wid] = m;
  __syncthreads();  // also guarantees all loads done before any in-place store
  m = fmaxf(fmaxf(redm[0], redm[1]), fmaxf(redm[2], redm[3]));

  float sum = 0.f;
  v4f e[4];
#pragma unroll
  for (int i = 0; i < 4; ++i)
#pragma unroll
    for (int j = 0; j < 4; ++j) {
      float t = __expf(v[i][j] - m);
      e[i][j] = t;
      sum += t;
    }
#pragma unroll
  for (int off = 32; off > 0; off >>= 1) sum += __shfl_xor(sum, off);
  if (lane == 0) reds[wid] = sum;
  __syncthreads();
  sum = reds[0] + reds[1] + reds[2] + reds[3];
  const float inv = 1.0f / sum;
#pragma unroll
  for (int i = 0; i < 4; ++i) {
    v4h o;
#pragma unroll
    for (int j = 0; j < 4; ++j) o[j] = (_Float16)(e[i][j] * inv);
    ((v4h*)p)[tid + i * 256] = o;
  }
}

__global__ __launch_bounds__(256) void cvt_f16(const float* __restrict__ in,
                                               _Float16* __restrict__ out, int n4) {
  int i = blockIdx.x * blockDim.x + threadIdx.x;
  if (i < n4) {
    v4f v = ((const v4f*)in)[i];
    v4h o;
#pragma unroll
    for (int j = 0; j < 4; ++j) o[j] = (_Float16)v[j];
    ((v4h*)out)[i] = o;
  }
}

// out[C][R] (f16) = in[R][C] (f32). Grid (C/32, R/32), 256 threads (32x8).
__global__ __launch_bounds__(256) void transpose_cvt(const float* __restrict__ in,
                                                     _Float16* __restrict__ out,
                                                     int R, int C) {
  __shared__ float tile[32][33];
  const int bx = blockIdx.x * 32;  // C base
  const int by = blockIdx.y * 32;  // R base
  const int tx = threadIdx.x & 31, ty = threadIdx.x >> 5;
#pragma unroll
  for (int i = 0; i < 32; i += 8)
    tile[ty + i][tx] = in[(size_t)(by + ty + i) * C + (bx + tx)];
  __syncthreads();
#pragma unroll
  for (int i = 0; i < 32; i += 8)
    out[(size_t)(bx + ty + i) * R + (by + tx)] = (_Float16)tile[tx][ty + i];
}

// Vt[b][d][n] = V[b][n][d], f16. Grid (DD/32, NN/32, BB).
__global__ __launch_bounds__(256) void transpose_v(const _Float16* __restrict__ in,
                                                   _Float16* __restrict__ out) {
  __shared__ _Float16 tile[32][33];
  const int b = blockIdx.z;
  const _Float16* src = in + (size_t)b * NN * DD;
  _Float16* dst = out + (size_t)b * NN * DD;
  const int bx = blockIdx.x * 32;  // DD base
  const int by = blockIdx.y * 32;  // NN base
  const int tx = threadIdx.x & 31, ty = threadIdx.x >> 5;
#pragma unroll
  for (int i = 0; i < 32; i += 8)
    tile[ty + i][tx] = src[(size_t)(by + ty + i) * DD + (bx + tx)];
  __syncthreads();
#pragma unroll
  for (int i = 0; i < 32; i += 8)
    dst[(size_t)(bx + ty + i) * NN + (by + tx)] = tile[tx][ty + i];
}

extern "C" void kernel_launch(void* const* d_in, const int* in_sizes, int n_in,
                              void* d_out, int out_size, void* d_ws, size_t ws_size,
                              hipStream_t stream) {
  const float* x = (const float*)d_in[0];      // [16384][768]
  const float* w_qkv = (const float*)d_in[1];  // [768][2304]
  const float* b_qkv = (const float*)d_in[2];  // [2304]
  const float* w_out = (const float*)d_in[3];  // [768][768]
  const float* b_out = (const float*)d_in[4];  // [768]
  float* out = (float*)d_out;                  // [16384][768]
  char* ws = (char*)d_ws;

  // ws layout (peak ~164.5 MB); regions reused once their producer is dead.
  _Float16* xh    = (_Float16*)(ws + 0);           // 25,165,824  (dead after QKV gemm)
  _Float16* wqkvh = (_Float16*)(ws + 25165824);    //  3,538,944  [2304][768] = W^T
  _Float16* wouth = (_Float16*)(ws + 28704768);    //  1,179,648  [768][768]  = Wout^T
  _Float16* Qh    = (_Float16*)(ws + 29884416);    // 25,165,824  (pre-scaled by 1/sqrt(D))
  _Float16* Kh    = (_Float16*)(ws + 55050240);    // 25,165,824
  _Float16* Vh    = (_Float16*)(ws + 80216064);    // 25,165,824  row-major V (dead after transpose)
  float*    Sb    = (float*)   (ws + 105381888);   // 67,108,864  one batch of scores
  _Float16* Vth   = (_Float16*)(ws + 0);           // reuse xh:  [4][768][4096]
  _Float16* Ch    = (_Float16*)(ws + 80216064);    // reuse Vh:  [16384][768] ctx f16

  // 1) precision converts / weight transposes
  cvt_f16<<<dim3((MTOT * DD / 4) / 256), 256, 0, stream>>>(x, xh, MTOT * DD / 4);
  transpose_cvt<<<dim3(EE / 32, DD / 32), 256, 0, stream>>>(w_qkv, wqkvh, DD, EE);
  transpose_cvt<<<dim3(DD / 32, DD / 32), 256, 0, stream>>>(w_out, wouth, DD, DD);

  // 2) fused QKV projection
  gemm128<EPI_QKV><<<dim3(MTOT / 128, EE / 128), 256, 0, stream>>>(
      xh, DD, wqkvh, DD, DD, nullptr, nullptr, 0, b_qkv, Qh, Kh, Vh);

  // 3) V -> V^T for the PV gemm's n-major B operand
  transpose_v<<<dim3(DD / 32, NN / 32, BB), 256, 0, stream>>>(Vh, Vth);

  // 4) per-batch: S = Q K^T (scale folded into Q) ; softmax ; ctx = P V
  for (int b = 0; b < BB; ++b) {
    const _Float16* Qb = Qh + (size_t)b * NN * DD;
    const _Float16* Kb = Kh + (size_t)b * NN * DD;
    const _Float16* Vtb = Vth + (size_t)b * NN * DD;
    _Float16* Cb = Ch + (size_t)b * NN * DD;
    gemm128<EPI_F32><<<dim3(NN / 128, NN / 128), 256, 0, stream>>>(
        Qb, DD, Kb, DD, DD, Sb, nullptr, NN, nullptr, nullptr, nullptr, nullptr);
    softmax_rows<<<dim3(NN), 256, 0, stream>>>(Sb);
    // P lives in-place in Sb: f16 values in the first half of each fp32 row,
    // so the PHYSICAL f16 row stride is 2*NN (8192), not NN.  (Round-1 NaN
    // root cause: lda=NN made odd rows read raw fp32 bytes as f16.)
    gemm128<EPI_F16><<<dim3(NN / 128, DD / 128), 256, 0, stream>>>(
        (const _Float16*)Sb, 2 * NN, Vtb, NN, NN, nullptr, Cb, DD, nullptr,
        nullptr, nullptr, nullptr);
  }

  // 5) output projection
  gemm128<EPI_OUT><<<dim3(MTOT / 128, DD / 128), 256, 0, stream>>>(
      Ch, DD, wouth, DD, DD, out, nullptr, DD, b_out, nullptr, nullptr, nullptr);
}

// Round 3
// 670.302 us; speedup vs baseline: 1.2415x; 1.2415x over previous
//
#include <hip/hip_runtime.h>
#include <cstdint>
#include <cstddef>

#define BB 4
#define NN 4096
#define DD 768
#define EE 2304      // 3*DD
#define MTOT 16384   // BB*NN
static constexpr float ATT_SCALE = 0.03608439182435161f;  // 1/sqrt(768)

typedef _Float16 v8h __attribute__((ext_vector_type(8)));
typedef _Float16 v4h __attribute__((ext_vector_type(4)));
typedef float v4f __attribute__((ext_vector_type(4)));

// Async global->LDS, 16B per lane. LDS dest = wave-uniform base + lane*16.
__device__ __forceinline__ void async_copy16(void* lds, const void* gmem) {
  __builtin_amdgcn_global_load_lds(
      (const __attribute__((address_space(1))) uint32_t*)(uintptr_t)gmem,
      (__attribute__((address_space(3))) uint32_t*)(uintptr_t)lds,
      16, 0, 0);
}

enum { EPI_QKV = 0, EPI_F32 = 1, EPI_F16 = 2, EPI_OUT = 3 };

// C[M,N] = A[M,K] @ Bt[N,K]^T.  A row-major (lda), Bt n-major (ldb).
// 128x128 tile, BK=32, 256 threads = 4 waves 2x2, 4x4 16x16x32 f16 MFMA each.
// z-batched: blockIdx.z adds zA/zB/zC element offsets to A/Bt/C.
template <int EPI>
__global__ __launch_bounds__(256) void gemm128(
    const _Float16* __restrict__ A, int lda, size_t zA,
    const _Float16* __restrict__ Bt, int ldb, size_t zB,
    int K,
    float* __restrict__ c_f32,
    _Float16* __restrict__ c_f16,
    int ldc, size_t zC,
    const float* __restrict__ bias,
    _Float16* __restrict__ q_out,
    _Float16* __restrict__ k_out,
    _Float16* __restrict__ v_out) {
  __shared__ __align__(16) _Float16 As[128 * 32];
  __shared__ __align__(16) _Float16 Bs[128 * 32];

  const int tid = threadIdx.x;
  const int wid = tid >> 6;
  const int lane = tid & 63;
  const int wr = wid >> 1, wc = wid & 1;       // wave grid 2x2 (64x64 each)
  const int lq = lane >> 4, lr = lane & 15;    // quad, row-in-tile
  const int m0 = blockIdx.x * 128, n0 = blockIdx.y * 128;
  const size_t zoff = blockIdx.z;

  const _Float16* Ab = A + zoff * zA + (size_t)m0 * lda;
  const _Float16* Bb = Bt + zoff * zB + (size_t)n0 * ldb;

  v4f acc[4][4] = {};

  for (int k0 = 0; k0 < K; k0 += 32) {
    // Stage 8KB A-tile + 8KB B-tile: 2 chunks of 16B per thread each.
    // LDS offset = c*16 bytes, per-wave contiguous (c = i*256 + wid*64 + lane).
#pragma unroll
    for (int i = 0; i < 2; ++i) {
      const int c = i * 256 + tid;
      const int r = c >> 2, kc = c & 3;
      async_copy16(As + (size_t)c * 8, Ab + (size_t)r * lda + (k0 + kc * 8));
      async_copy16(Bs + (size_t)c * 8, Bb + (size_t)r * ldb + (k0 + kc * 8));
    }
    __syncthreads();

    v8h af[4], bf[4];
#pragma unroll
    for (int t = 0; t < 4; ++t) {
      af[t] = *(const v8h*)(As + ((wr * 64 + t * 16 + lr) * 32 + lq * 8));
      bf[t] = *(const v8h*)(Bs + ((wc * 64 + t * 16 + lr) * 32 + lq * 8));
    }
#pragma unroll
    for (int mt = 0; mt < 4; ++mt)
#pragma unroll
      for (int nt = 0; nt < 4; ++nt)
        acc[mt][nt] = __builtin_amdgcn_mfma_f32_16x16x32_f16(
            af[mt], bf[nt], acc[mt][nt], 0, 0, 0);
    __syncthreads();
  }

  // Epilogue. C/D frag: col = lane&15, row = (lane>>4)*4 + reg (m89/m91).
  float* cf = c_f32 ? c_f32 + zoff * zC : nullptr;
  _Float16* ch = c_f16 ? c_f16 + zoff * zC : nullptr;
#pragma unroll
  for (int mt = 0; mt < 4; ++mt) {
#pragma unroll
    for (int nt = 0; nt < 4; ++nt) {
#pragma unroll
      for (int rg = 0; rg < 4; ++rg) {
        const int gm = m0 + wr * 64 + mt * 16 + lq * 4 + rg;
        const int gn = n0 + wc * 64 + nt * 16 + lr;
        float v = acc[mt][nt][rg];
        if constexpr (EPI == EPI_QKV) {
          v += bias[gn];
          if (gn < DD) {            // block-uniform branches (multiples of 128)
            q_out[(size_t)gm * DD + gn] = (_Float16)(v * ATT_SCALE);
          } else if (gn < 2 * DD) {
            k_out[(size_t)gm * DD + (gn - DD)] = (_Float16)v;
          } else {
            v_out[(size_t)gm * DD + (gn - 2 * DD)] = (_Float16)v;
          }
        } else if constexpr (EPI == EPI_F32) {
          cf[(size_t)gm * ldc + gn] = v;
        } else if constexpr (EPI == EPI_F16) {
          ch[(size_t)gm * ldc + gn] = (_Float16)v;
        } else {  // EPI_OUT
          cf[(size_t)gm * ldc + gn] = v + bias[gn];
        }
      }
    }
  }
}

// Row softmax over f16 scores, in place, f16 P out.  Grid (NN, nz); one block
// per row; S row = S + blockIdx.y*NN*NN + blockIdx.x*NN.  Each thread owns the
// exact elements it rewrites (no cross-thread aliasing).
__global__ __launch_bounds__(256) void softmax_rows_f16(_Float16* __restrict__ S) {
  _Float16* row = S + (size_t)blockIdx.y * NN * NN + (size_t)blockIdx.x * NN;
  const int tid = threadIdx.x;
  const int lane = tid & 63, wid = tid >> 6;

  float f[16];
  float m = -3.0e38f;
#pragma unroll
  for (int i = 0; i < 2; ++i) {
    v8h v = ((const v8h*)row)[tid + i * 256];
#pragma unroll
    for (int j = 0; j < 8; ++j) {
      f[i * 8 + j] = (float)v[j];
      m = fmaxf(m, f[i * 8 + j]);
    }
  }
#pragma unroll
  for (int off = 32; off > 0; off >>= 1) m = fmaxf(m, __shfl_xor(m, off));
  __shared__ float redm[4], reds[4];
  if (lane == 0) redm[wid] = m;
  __syncthreads();
  m = fmaxf(fmaxf(redm[0], redm[1]), fmaxf(redm[2], redm[3]));

  float sum = 0.f;
#pragma unroll
  for (int i = 0; i < 16; ++i) {
    f[i] = __expf(f[i] - m);
    sum += f[i];
  }
#pragma unroll
  for (int off = 32; off > 0; off >>= 1) sum += __shfl_xor(sum, off);
  if (lane == 0) reds[wid] = sum;
  __syncthreads();
  sum = reds[0] + reds[1] + reds[2] + reds[3];
  const float inv = 1.0f / sum;
#pragma unroll
  for (int i = 0; i < 2; ++i) {
    v8h o;
#pragma unroll
    for (int j = 0; j < 8; ++j) o[j] = (_Float16)(f[i * 8 + j] * inv);
    ((v8h*)row)[tid + i * 256] = o;
  }
}

__global__ __launch_bounds__(256) void cvt_f16(const float* __restrict__ in,
                                               _Float16* __restrict__ out, int n4) {
  int i = blockIdx.x * blockDim.x + threadIdx.x;
  if (i < n4) {
    v4f v = ((const v4f*)in)[i];
    v4h o;
#pragma unroll
    for (int j = 0; j < 4; ++j) o[j] = (_Float16)v[j];
    ((v4h*)out)[i] = o;
  }
}

// out[C][R] (f16) = in[R][C] (f32). Grid (C/32, R/32), 256 threads (32x8).
__global__ __launch_bounds__(256) void transpose_cvt(const float* __restrict__ in,
                                                     _Float16* __restrict__ out,
                                                     int R, int C) {
  __shared__ float tile[32][33];
  const int bx = blockIdx.x * 32;  // C base
  const int by = blockIdx.y * 32;  // R base
  const int tx = threadIdx.x & 31, ty = threadIdx.x >> 5;
#pragma unroll
  for (int i = 0; i < 32; i += 8)
    tile[ty + i][tx] = in[(size_t)(by + ty + i) * C + (bx + tx)];
  __syncthreads();
#pragma unroll
  for (int i = 0; i < 32; i += 8)
    out[(size_t)(bx + ty + i) * R + (by + tx)] = (_Float16)tile[tx][ty + i];
}

// Vt[b][d][n] = V[b][n][d], f16. Grid (DD/32, NN/32, BB).
__global__ __launch_bounds__(256) void transpose_v(const _Float16* __restrict__ in,
                                                   _Float16* __restrict__ out) {
  __shared__ _Float16 tile[32][33];
  const int b = blockIdx.z;
  const _Float16* src = in + (size_t)b * NN * DD;
  _Float16* dst = out + (size_t)b * NN * DD;
  const int bx = blockIdx.x * 32;  // DD base
  const int by = blockIdx.y * 32;  // NN base
  const int tx = threadIdx.x & 31, ty = threadIdx.x >> 5;
#pragma unroll
  for (int i = 0; i < 32; i += 8)
    tile[ty + i][tx] = src[(size_t)(by + ty + i) * DD + (bx + tx)];
  __syncthreads();
#pragma unroll
  for (int i = 0; i < 32; i += 8)
    dst[(size_t)(bx + ty + i) * NN + (by + tx)] = tile[tx][ty + i];
}

extern "C" void kernel_launch(void* const* d_in, const int* in_sizes, int n_in,
                              void* d_out, int out_size, void* d_ws, size_t ws_size,
                              hipStream_t stream) {
  const float* x = (const float*)d_in[0];      // [16384][768]
  const float* w_qkv = (const float*)d_in[1];  // [768][2304]
  const float* b_qkv = (const float*)d_in[2];  // [2304]
  const float* w_out = (const float*)d_in[3];  // [768][768]
  const float* b_out = (const float*)d_in[4];  // [768]
  float* out = (float*)d_out;                  // [16384][768]
  char* ws = (char*)d_ws;

  // ws layout, peak 169.4 MB (< 172.5 MB already proven in round 2):
  _Float16* xh    = (_Float16*)(ws + 0);           // 25 MB  (dead after QKV gemm)
  _Float16* wqkvh = (_Float16*)(ws + 25165824);    // 3.5 MB [2304][768] = W^T
  _Float16* wouth = (_Float16*)(ws + 28704768);    // 1.2 MB [768][768]  = Wout^T
  _Float16* Qh    = (_Float16*)(ws + 29884416);    // 25 MB  (pre-scaled)
  _Float16* Kh    = (_Float16*)(ws + 55050240);    // 25 MB
  _Float16* Vh    = (_Float16*)(ws + 80216064);    // 25 MB  (dead after transpose)
  _Float16* Sh    = (_Float16*)(ws + 105381888);   // 64 MB  f16 scores, 2 batches
  _Float16* Vth   = (_Float16*)(ws + 0);           // reuse xh: [4][768][4096]
  _Float16* Ch    = (_Float16*)(ws + 80216064);    // reuse Vh: [16384][768] ctx

  // 1) precision converts / weight transposes
  cvt_f16<<<dim3((MTOT * DD / 4) / 256), 256, 0, stream>>>(x, xh, MTOT * DD / 4);
  transpose_cvt<<<dim3(EE / 32, DD / 32), 256, 0, stream>>>(w_qkv, wqkvh, DD, EE);
  transpose_cvt<<<dim3(DD / 32, DD / 32), 256, 0, stream>>>(w_out, wouth, DD, DD);

  // 2) fused QKV projection (scale folded into Q)
  gemm128<EPI_QKV><<<dim3(MTOT / 128, EE / 128), 256, 0, stream>>>(
      xh, DD, 0, wqkvh, DD, 0, DD, nullptr, nullptr, 0, 0, b_qkv, Qh, Kh, Vh);

  // 3) V -> V^T for the PV gemm's n-major B operand
  transpose_v<<<dim3(DD / 32, NN / 32, BB), 256, 0, stream>>>(Vh, Vth);

  // 4) attention in 2-batch chunks (z-batched): S=QK^T (f16) ; softmax ; ctx=PV
  const size_t zQK = (size_t)NN * DD;  // per-batch stride of Q/K/Vt/C
  const size_t zS = (size_t)NN * NN;   // per-batch stride of S
  for (int c = 0; c < BB / 2; ++c) {
    const _Float16* Qc = Qh + (size_t)c * 2 * zQK;
    const _Float16* Kc = Kh + (size_t)c * 2 * zQK;
    const _Float16* Vtc = Vth + (size_t)c * 2 * zQK;
    _Float16* Cc = Ch + (size_t)c * 2 * zQK;
    gemm128<EPI_F16><<<dim3(NN / 128, NN / 128, 2), 256, 0, stream>>>(
        Qc, DD, zQK, Kc, DD, zQK, DD, nullptr, Sh, NN, zS, nullptr, nullptr,
        nullptr, nullptr);
    softmax_rows_f16<<<dim3(NN, 2), 256, 0, stream>>>(Sh);
    gemm128<EPI_F16><<<dim3(NN / 128, DD / 128, 2), 256, 0, stream>>>(
        Sh, NN, zS, Vtc, NN, zQK, NN, nullptr, Cc, DD, zQK, nullptr, nullptr,
        nullptr, nullptr);
  }

  // 5) output projection
  gemm128<EPI_OUT><<<dim3(MTOT / 128, DD / 128), 256, 0, stream>>>(
      Ch, DD, 0, wouth, DD, 0, DD, out, nullptr, DD, 0, b_out, nullptr, nullptr,
      nullptr);
}

// Round 4
// 576.834 us; speedup vs baseline: 1.4427x; 1.1620x over previous
//
#include <hip/hip_runtime.h>
#include <cstdint>
#include <cstddef>

#define BB 4
#define NN 4096
#define DD 768
#define EE 2304      // 3*DD
#define MTOT 16384   // BB*NN
static constexpr float ATT_SCALE = 0.03608439182435161f;  // 1/sqrt(768)

typedef _Float16 v8h __attribute__((ext_vector_type(8)));
typedef _Float16 v4h __attribute__((ext_vector_type(4)));
typedef float v4f __attribute__((ext_vector_type(4)));

// Async global->LDS, 16B per lane. LDS dest = wave-uniform base + lane*16.
__device__ __forceinline__ void async_copy16(void* lds, const void* gmem) {
  __builtin_amdgcn_global_load_lds(
      (const __attribute__((address_space(1))) uint32_t*)(uintptr_t)gmem,
      (__attribute__((address_space(3))) uint32_t*)(uintptr_t)lds,
      16, 0, 0);
}

enum { EPI_QKV = 0, EPI_F16 = 1, EPI_OUT = 2, EPI_PV = 3 };

// C[M,N] = A[M,K] @ Bt[N,K]^T.  A row-major (lda), Bt n-major (ldb).
// 128x128 tile, BK=64 (32 KB LDS), 256 threads = 4 waves 2x2, 4x4 16x16x32 MFMA.
// LDS layout: row-major 128x64 with XOR chunk swizzle — row r's 16B chunk at
// logical col-chunk cb lives at physical chunk (cb ^ (r&7)).  The swizzle is
// applied on the STAGING side (choice of gmem source per lane; LDS dest is
// lane-pinned by global_load_lds) so ds_read_b128 spreads across all 32 banks
// (2 rows/bank = free) instead of 16-way conflicts at the 128 B row stride.
// EPI_PV: blockIdx.z = khalf*2 + batch; k-range [khalf*K, khalf*K+K);
//         C = c_f32 + khalf*chalf + batch*zC (plain f32 partial stores).
// Other EPIs: blockIdx.z = batch (offsets zA/zB/zC).
template <int EPI>
__global__ __launch_bounds__(256) void gemm128(
    const _Float16* __restrict__ A, int lda, size_t zA,
    const _Float16* __restrict__ Bt, int ldb, size_t zB,
    int K,
    float* __restrict__ c_f32,
    _Float16* __restrict__ c_f16,
    int ldc, size_t zC, size_t chalf,
    const float* __restrict__ bias,
    _Float16* __restrict__ q_out,
    _Float16* __restrict__ k_out,
    _Float16* __restrict__ v_out) {
  __shared__ __align__(16) _Float16 As[128 * 64];
  __shared__ __align__(16) _Float16 Bs[128 * 64];

  const int tid = threadIdx.x;
  const int wid = tid >> 6, lane = tid & 63;
  const int wr = wid >> 1, wc = wid & 1;       // wave grid 2x2 (64x64 each)
  const int lq = lane >> 4, lr = lane & 15;    // quad, row-in-tile
  const int m0 = blockIdx.x * 128, n0 = blockIdx.y * 128;
  const int z = blockIdx.z;
  int bidx, koff;
  if constexpr (EPI == EPI_PV) {
    bidx = z & 1;            // batch within chunk
    koff = (z >> 1) * K;     // k-half offset
  } else {
    bidx = z;
    koff = 0;
  }

  const _Float16* Ab = A + (size_t)bidx * zA + (size_t)m0 * lda + koff;
  const _Float16* Bb = Bt + (size_t)bidx * zB + (size_t)n0 * ldb + koff;

  v4f acc[4][4] = {};

  for (int k0 = 0; k0 < K; k0 += 64) {
    // Stage 16KB A + 16KB B: 1024 chunks of 16B each, 4 per thread per matrix.
    // chunk c: row r=c>>3; LDS gets physical chunk position c&7, whose logical
    // (gmem) col-chunk is (c&7)^(r&7).
#pragma unroll
    for (int i = 0; i < 4; ++i) {
      const int c = i * 256 + tid;
      const int r = c >> 3;
      const int kc = (c & 7) ^ (r & 7);
      async_copy16(As + (size_t)c * 8, Ab + (size_t)r * lda + (k0 + kc * 8));
      async_copy16(Bs + (size_t)c * 8, Bb + (size_t)r * ldb + (k0 + kc * 8));
    }
    __syncthreads();

#pragma unroll
    for (int ks = 0; ks < 2; ++ks) {
      v8h af[4], bf[4];
#pragma unroll
      for (int t = 0; t < 4; ++t) {
        const int ra = wr * 64 + t * 16 + lr;
        const int rb = wc * 64 + t * 16 + lr;
        const int cb = ks * 4 + lq;
        af[t] = *(const v8h*)(As + ra * 64 + (((cb ^ (ra & 7)) << 3)));
        bf[t] = *(const v8h*)(Bs + rb * 64 + (((cb ^ (rb & 7)) << 3)));
      }
#pragma unroll
      for (int mt = 0; mt < 4; ++mt)
#pragma unroll
        for (int nt = 0; nt < 4; ++nt)
          acc[mt][nt] = __builtin_amdgcn_mfma_f32_16x16x32_f16(
              af[mt], bf[nt], acc[mt][nt], 0, 0, 0);
    }
    __syncthreads();
  }

  // Epilogue. C/D frag: col = lane&15, row = (lane>>4)*4 + reg (m89/m91).
  float* cf = nullptr;
  _Float16* ch = nullptr;
  if constexpr (EPI == EPI_PV)
    cf = c_f32 + (size_t)(z >> 1) * chalf + (size_t)bidx * zC;
  else if constexpr (EPI == EPI_OUT)
    cf = c_f32 + (size_t)bidx * zC;
  else if constexpr (EPI == EPI_F16)
    ch = c_f16 + (size_t)bidx * zC;

#pragma unroll
  for (int mt = 0; mt < 4; ++mt) {
#pragma unroll
    for (int nt = 0; nt < 4; ++nt) {
#pragma unroll
      for (int rg = 0; rg < 4; ++rg) {
        const int gm = m0 + wr * 64 + mt * 16 + lq * 4 + rg;
        const int gn = n0 + wc * 64 + nt * 16 + lr;
        float v = acc[mt][nt][rg];
        if constexpr (EPI == EPI_QKV) {
          v += bias[gn];
          if (gn < DD) {            // block-uniform branches (multiples of 128)
            q_out[(size_t)gm * DD + gn] = (_Float16)(v * ATT_SCALE);
          } else if (gn < 2 * DD) {
            k_out[(size_t)gm * DD + (gn - DD)] = (_Float16)v;
          } else {
            v_out[(size_t)gm * DD + (gn - 2 * DD)] = (_Float16)v;
          }
        } else if constexpr (EPI == EPI_F16) {
          ch[(size_t)gm * ldc + gn] = (_Float16)v;
        } else {  // EPI_PV / EPI_OUT
          cf[(size_t)gm * ldc + gn] = (EPI == EPI_OUT) ? v + bias[gn] : v;
        }
      }
    }
  }
}

// ctx f16 = half0 + half1 (split-K reduce + f32->f16 convert).
__global__ __launch_bounds__(256) void reduce_ctx(const float* __restrict__ h0,
                                                  const float* __restrict__ h1,
                                                  _Float16* __restrict__ out,
                                                  int n4) {
  int i = blockIdx.x * blockDim.x + threadIdx.x;
  if (i < n4) {
    v4f a = ((const v4f*)h0)[i];
    v4f b = ((const v4f*)h1)[i];
    v4h o;
#pragma unroll
    for (int j = 0; j < 4; ++j) o[j] = (_Float16)(a[j] + b[j]);
    ((v4h*)out)[i] = o;
  }
}

// Row softmax over f16 scores, in place. Grid (NN, nz); one block per row.
__global__ __launch_bounds__(256) void softmax_rows_f16(_Float16* __restrict__ S) {
  _Float16* row = S + (size_t)blockIdx.y * NN * NN + (size_t)blockIdx.x * NN;
  const int tid = threadIdx.x;
  const int lane = tid & 63, wid = tid >> 6;

  float f[16];
  float m = -3.0e38f;
#pragma unroll
  for (int i = 0; i < 2; ++i) {
    v8h v = ((const v8h*)row)[tid + i * 256];
#pragma unroll
    for (int j = 0; j < 8; ++j) {
      f[i * 8 + j] = (float)v[j];
      m = fmaxf(m, f[i * 8 + j]);
    }
  }
#pragma unroll
  for (int off = 32; off > 0; off >>= 1) m = fmaxf(m, __shfl_xor(m, off));
  __shared__ float redm[4], reds[4];
  if (lane == 0) redm[wid] = m;
  __syncthreads();
  m = fmaxf(fmaxf(redm[0], redm[1]), fmaxf(redm[2], redm[3]));

  float sum = 0.f;
#pragma unroll
  for (int i = 0; i < 16; ++i) {
    f[i] = __expf(f[i] - m);
    sum += f[i];
  }
#pragma unroll
  for (int off = 32; off > 0; off >>= 1) sum += __shfl_xor(sum, off);
  if (lane == 0) reds[wid] = sum;
  __syncthreads();
  sum = reds[0] + reds[1] + reds[2] + reds[3];
  const float inv = 1.0f / sum;
#pragma unroll
  for (int i = 0; i < 2; ++i) {
    v8h o;
#pragma unroll
    for (int j = 0; j < 8; ++j) o[j] = (_Float16)(f[i * 8 + j] * inv);
    ((v8h*)row)[tid + i * 256] = o;
  }
}

__global__ __launch_bounds__(256) void cvt_f16(const float* __restrict__ in,
                                               _Float16* __restrict__ out, int n4) {
  int i = blockIdx.x * blockDim.x + threadIdx.x;
  if (i < n4) {
    v4f v = ((const v4f*)in)[i];
    v4h o;
#pragma unroll
    for (int j = 0; j < 4; ++j) o[j] = (_Float16)v[j];
    ((v4h*)out)[i] = o;
  }
}

// out[C][R] (f16) = in[R][C] (f32). Grid (C/32, R/32), 256 threads (32x8).
__global__ __launch_bounds__(256) void transpose_cvt(const float* __restrict__ in,
                                                     _Float16* __restrict__ out,
                                                     int R, int C) {
  __shared__ float tile[32][33];
  const int bx = blockIdx.x * 32;  // C base
  const int by = blockIdx.y * 32;  // R base
  const int tx = threadIdx.x & 31, ty = threadIdx.x >> 5;
#pragma unroll
  for (int i = 0; i < 32; i += 8)
    tile[ty + i][tx] = in[(size_t)(by + ty + i) * C + (bx + tx)];
  __syncthreads();
#pragma unroll
  for (int i = 0; i < 32; i += 8)
    out[(size_t)(bx + ty + i) * R + (by + tx)] = (_Float16)tile[tx][ty + i];
}

// Vt[b][d][n] = V[b][n][d], f16. Grid (DD/32, NN/32, BB).
__global__ __launch_bounds__(256) void transpose_v(const _Float16* __restrict__ in,
                                                   _Float16* __restrict__ out) {
  __shared__ _Float16 tile[32][33];
  const int b = blockIdx.z;
  const _Float16* src = in + (size_t)b * NN * DD;
  _Float16* dst = out + (size_t)b * NN * DD;
  const int bx = blockIdx.x * 32;  // DD base
  const int by = blockIdx.y * 32;  // NN base
  const int tx = threadIdx.x & 31, ty = threadIdx.x >> 5;
#pragma unroll
  for (int i = 0; i < 32; i += 8)
    tile[ty + i][tx] = src[(size_t)(by + ty + i) * DD + (bx + tx)];
  __syncthreads();
#pragma unroll
  for (int i = 0; i < 32; i += 8)
    dst[(size_t)(bx + ty + i) * NN + (by + tx)] = tile[tx][ty + i];
}

extern "C" void kernel_launch(void* const* d_in, const int* in_sizes, int n_in,
                              void* d_out, int out_size, void* d_ws, size_t ws_size,
                              hipStream_t stream) {
  const float* x = (const float*)d_in[0];      // [16384][768]
  const float* w_qkv = (const float*)d_in[1];  // [768][2304]
  const float* b_qkv = (const float*)d_in[2];  // [2304]
  const float* w_out = (const float*)d_in[3];  // [768][768]
  const float* b_out = (const float*)d_in[4];  // [768]
  float* out = (float*)d_out;                  // [16384][768] — also used as
                                               // split-K f32 partial scratch
  char* ws = (char*)d_ws;

  // ws layout, peak 164.5 MB (same as round 3, proven):
  _Float16* xh    = (_Float16*)(ws + 0);           // 25 MB  (dead after QKV gemm)
  _Float16* wqkvh = (_Float16*)(ws + 25165824);    // 3.5 MB [2304][768] = W^T
  _Float16* wouth = (_Float16*)(ws + 28704768);    // 1.2 MB [768][768]  = Wout^T
  _Float16* Qh    = (_Float16*)(ws + 29884416);    // 25 MB  (pre-scaled)
  _Float16* Kh    = (_Float16*)(ws + 55050240);    // 25 MB
  _Float16* Vh    = (_Float16*)(ws + 80216064);    // 25 MB  (dead after transpose)
  _Float16* Sh    = (_Float16*)(ws + 105381888);   // 64 MB  f16 scores, 2 batches
  _Float16* Vth   = (_Float16*)(ws + 0);           // reuse xh: [4][768][4096]
  _Float16* Ch    = (_Float16*)(ws + 80216064);    // reuse Vh: [16384][768] ctx

  const size_t zQK = (size_t)NN * DD;   // per-batch stride Q/K/Vt/C (f16 elems)
  const size_t zS = (size_t)NN * NN;    // per-batch stride S (f16 elems)
  const size_t zCtx = (size_t)NN * DD;  // per-batch stride ctx partial (f32)
  const size_t chalf = 2 * zCtx;        // k-half stride in d_out (f32 elems)

  // 1) precision converts / weight transposes
  cvt_f16<<<dim3((MTOT * DD / 4) / 256), 256, 0, stream>>>(x, xh, MTOT * DD / 4);
  transpose_cvt<<<dim3(EE / 32, DD / 32), 256, 0, stream>>>(w_qkv, wqkvh, DD, EE);
  transpose_cvt<<<dim3(DD / 32, DD / 32), 256, 0, stream>>>(w_out, wouth, DD, DD);

  // 2) fused QKV projection (scale folded into Q)
  gemm128<EPI_QKV><<<dim3(MTOT / 128, EE / 128), 256, 0, stream>>>(
      xh, DD, 0, wqkvh, DD, 0, DD, nullptr, nullptr, 0, 0, 0, b_qkv, Qh, Kh, Vh);

  // 3) V -> V^T for the PV gemm's n-major B operand
  transpose_v<<<dim3(DD / 32, NN / 32, BB), 256, 0, stream>>>(Vh, Vth);

  // 4) attention in 2-batch chunks: S=QK^T (f16) ; softmax ; ctx=PV split-K=2
  //    PV partials: plain f32 stores into the two halves of d_out (50.3 MB =
  //    exactly 2 halves x 2 batches x 4096 x 768 f32), then reduce to Ch f16.
  for (int c = 0; c < BB / 2; ++c) {
    const _Float16* Qc = Qh + (size_t)c * 2 * zQK;
    const _Float16* Kc = Kh + (size_t)c * 2 * zQK;
    const _Float16* Vtc = Vth + (size_t)c * 2 * zQK;
    gemm128<EPI_F16><<<dim3(NN / 128, NN / 128, 2), 256, 0, stream>>>(
        Qc, DD, zQK, Kc, DD, zQK, DD, nullptr, Sh, NN, zS, 0, nullptr, nullptr,
        nullptr, nullptr);
    softmax_rows_f16<<<dim3(NN, 2), 256, 0, stream>>>(Sh);
    gemm128<EPI_PV><<<dim3(NN / 128, DD / 128, 4), 256, 0, stream>>>(
        Sh, NN, zS, Vtc, NN, zQK, NN / 2, out, nullptr, DD, zCtx, chalf,
        nullptr, nullptr, nullptr, nullptr);
    reduce_ctx<<<dim3((int)(chalf / 4 / 256)), 256, 0, stream>>>(
        out, out + chalf, Ch + (size_t)c * 2 * zQK, (int)(chalf / 4));
  }

  // 5) output projection (reads Ch f16; overwrites d_out with final f32+bias)
  gemm128<EPI_OUT><<<dim3(MTOT / 128, DD / 128), 256, 0, stream>>>(
      Ch, DD, 0, wouth, DD, 0, DD, out, nullptr, DD, 0, 0, b_out, nullptr,
      nullptr, nullptr);
}